// Round 8
// baseline (250.550 us; speedup 1.0000x reference)
//
#include <hip/hip_runtime.h>
#include <math.h>

#define BATCH   128
#define NUSER   10000
#define NITEM   10000
#define EDIM    64
#define FUDIM   8
#define FIDIM   8
#define INDIM   144   // 2*EDIM + FUDIM + FIDIM

typedef float v4f __attribute__((ext_vector_type(4)));

// d_out layout (floats):
// [0, 8192)                      new_user        (B x E)
// [8192, 16384)                  new_item        (B x E)
// [16384, 16384+81920000)        new_user_memory (B x NU x E)
// [16384+81920000, ...)          new_item_memory (B x NI x E)
#define OFF_NI   ((long)BATCH * EDIM)
#define OFF_UM   ((long)2 * BATCH * EDIM)
#define MEM_ELTS ((long)BATCH * NUSER * EDIM)
#define OFF_IM   (OFF_UM + MEM_ELTS)
#define NBLK_PER_MEM ((int)(MEM_ELTS / 4 / 256))   // 80,000
#define GRU_BLOCKS   64                            // 64 blocks x 4 waves = 256 units

// Single fused launch:
//   blocks [0, 80000)        : copy um -> out_um, skipping modified rows
//   blocks [80000, 160000)   : copy im -> out_im, skipping modified rows
//   blocks [160000, 160064)  : GRU + L2norm; writes new_user/new_item AND the
//                              modified memory rows (disjoint from copy writes,
//                              so no inter-block ordering is required).
__global__ __launch_bounds__(256) void limnet_fused_kernel(
    const float* __restrict__ um, const float* __restrict__ im,
    const int* __restrict__ uids, const int* __restrict__ iids,
    const float* __restrict__ ufeat, const float* __restrict__ ifeat,
    const float* __restrict__ u_w_ih, const float* __restrict__ u_b_ih,
    const float* __restrict__ u_b_hh,
    const float* __restrict__ i_w_ih, const float* __restrict__ i_b_ih,
    const float* __restrict__ i_b_hh,
    float* __restrict__ out)
{
    const int blk = blockIdx.x;

    if (blk < 2 * NBLK_PER_MEM) {
        // ---------------- copy path ----------------
        const bool isU = blk < NBLK_PER_MEM;
        const int  lblk = isU ? blk : blk - NBLK_PER_MEM;
        const v4f* __restrict__ src = isU ? (const v4f*)um : (const v4f*)im;
        v4f* __restrict__ dst = isU ? (v4f*)(out + OFF_UM) : (v4f*)(out + OFF_IM);
        const int* __restrict__ ids = isU ? uids : iids;

        const long i   = (long)lblk * 256 + threadIdx.x;
        const int  row = (int)(i >> 4);            // 16 float4s per 64-float row
        const int  b   = row / NUSER;              // compiler magic-mul
        const int  idx = row - b * NUSER;

        const v4f val = __builtin_nontemporal_load(&src[i]);
        if (idx != ids[b])                          // modified row -> GRU writes it
            __builtin_nontemporal_store(val, &dst[i]);
        return;
    }

    // ---------------- GRU path: 4 waves/block, 1 unit/wave ----------------
    const int unit  = (blk - 2 * NBLK_PER_MEM) * 4 + (threadIdx.x >> 6); // 0..255
    const int b     = unit >> 1;
    const int which = unit & 1;     // 0 = user GRU, 1 = item GRU
    const int lane  = threadIdx.x & 63;
    const int wv    = threadIdx.x >> 6;

    __shared__ float xs[4][INDIM];
    float* x = xs[wv];

    const int uid = uids[b];
    const int iid = iids[b];
    const float* ue = um + ((long)b * NUSER + uid) * EDIM;
    const float* ie = im + ((long)b * NITEM + iid) * EDIM;

    if (which == 0) {
        // [user_emb(64), user_feat(8), item_emb(64), item_feat(8)]
        x[lane] = ue[lane];
        x[EDIM + FUDIM + lane] = ie[lane];
        if (lane < FUDIM) x[EDIM + lane] = ufeat[b * FUDIM + lane];
        if (lane < FIDIM) x[EDIM + FUDIM + EDIM + lane] = ifeat[b * FIDIM + lane];
    } else {
        // [item_emb(64), item_feat(8), user_emb(64), user_feat(8)]
        x[lane] = ie[lane];
        x[EDIM + FIDIM + lane] = ue[lane];
        if (lane < FIDIM) x[EDIM + lane] = ifeat[b * FIDIM + lane];
        if (lane < FUDIM) x[EDIM + FIDIM + EDIM + lane] = ufeat[b * FUDIM + lane];
    }
    __syncthreads();

    const float* w   = which ? i_w_ih : u_w_ih;
    const float* bih = which ? i_b_ih : u_b_ih;
    const float* bhh = which ? i_b_hh : u_b_hh;

    // h0 == 0  =>  gh = b_hh exactly; GRU collapses to gates on gi only.
    float gr = bih[lane];
    float gz = bih[EDIM + lane];
    float gn = bih[2 * EDIM + lane];
    const v4f* wr = (const v4f*)(w + (long)lane * INDIM);
    const v4f* wz = (const v4f*)(w + (long)(EDIM + lane) * INDIM);
    const v4f* wn = (const v4f*)(w + (long)(2 * EDIM + lane) * INDIM);
    #pragma unroll 4
    for (int k4 = 0; k4 < INDIM / 4; ++k4) {
        const v4f vr = wr[k4];
        const v4f vz = wz[k4];
        const v4f vn = wn[k4];
        const float x0 = x[4 * k4 + 0], x1 = x[4 * k4 + 1];
        const float x2 = x[4 * k4 + 2], x3 = x[4 * k4 + 3];
        gr = fmaf(vr.x, x0, gr); gr = fmaf(vr.y, x1, gr);
        gr = fmaf(vr.z, x2, gr); gr = fmaf(vr.w, x3, gr);
        gz = fmaf(vz.x, x0, gz); gz = fmaf(vz.y, x1, gz);
        gz = fmaf(vz.z, x2, gz); gz = fmaf(vz.w, x3, gz);
        gn = fmaf(vn.x, x0, gn); gn = fmaf(vn.y, x1, gn);
        gn = fmaf(vn.z, x2, gn); gn = fmaf(vn.w, x3, gn);
    }
    const float r = 1.0f / (1.0f + expf(-(gr + bhh[lane])));
    const float z = 1.0f / (1.0f + expf(-(gz + bhh[EDIM + lane])));
    const float n = tanhf(gn + r * bhh[2 * EDIM + lane]);
    const float h = (1.0f - z) * n;     // + z*h0, h0 == 0

    // L2 normalize across the 64-lane wave.
    float s = h * h;
    #pragma unroll
    for (int off = 32; off; off >>= 1) s += __shfl_xor(s, off, 64);
    const float val = h / fmaxf(sqrtf(s), 1e-12f);

    if (which == 0) {
        out[(long)b * EDIM + lane] = val;
        out[OFF_UM + ((long)b * NUSER + uid) * EDIM + lane] = val;
    } else {
        out[OFF_NI + (long)b * EDIM + lane] = val;
        out[OFF_IM + ((long)b * NITEM + iid) * EDIM + lane] = val;
    }
}

extern "C" void kernel_launch(void* const* d_in, const int* in_sizes, int n_in,
                              void* d_out, int out_size, void* d_ws, size_t ws_size,
                              hipStream_t stream) {
    const float* um    = (const float*)d_in[0];
    const float* im    = (const float*)d_in[1];
    const int*   uids  = (const int*)d_in[2];
    const int*   iids  = (const int*)d_in[3];
    const float* ufeat = (const float*)d_in[4];
    const float* ifeat = (const float*)d_in[5];
    const float* u_w_ih = (const float*)d_in[6];
    // d_in[7] = u_w_hh (unused: h0 == 0)
    const float* u_b_ih = (const float*)d_in[8];
    const float* u_b_hh = (const float*)d_in[9];
    const float* i_w_ih = (const float*)d_in[10];
    // d_in[11] = i_w_hh (unused)
    const float* i_b_ih = (const float*)d_in[12];
    const float* i_b_hh = (const float*)d_in[13];
    float* out = (float*)d_out;

    // Single fused launch: copy (160k blocks) + GRU (64 blocks), disjoint writes.
    limnet_fused_kernel<<<2 * NBLK_PER_MEM + GRU_BLOCKS, 256, 0, stream>>>(
        um, im, uids, iids, ufeat, ifeat,
        u_w_ih, u_b_ih, u_b_hh,
        i_w_ih, i_b_ih, i_b_hh,
        out);
}

// Round 9
// 212.994 us; speedup vs baseline: 1.1763x; 1.1763x over previous
//
#include <hip/hip_runtime.h>
#include <math.h>

#define BATCH   128
#define NUSER   10000
#define NITEM   10000
#define EDIM    64
#define FUDIM   8
#define FIDIM   8
#define INDIM   144   // 2*EDIM + FUDIM + FIDIM

typedef float v4f __attribute__((ext_vector_type(4)));

// d_out layout (floats):
// [0, 8192)                      new_user        (B x E)
// [8192, 16384)                  new_item        (B x E)
// [16384, 16384+81920000)        new_user_memory (B x NU x E)
// [16384+81920000, ...)          new_item_memory (B x NI x E)
#define OFF_NI   ((long)BATCH * EDIM)
#define OFF_UM   ((long)2 * BATCH * EDIM)
#define MEM_ELTS ((long)BATCH * NUSER * EDIM)
#define OFF_IM   (OFF_UM + MEM_ELTS)
#define NBLK_PER_MEM ((int)(MEM_ELTS / 4 / 256))   // 80,000

// R7 winner: fused one-shot copy. 1 float4/thread, NT both ways, 8 VGPRs.
__global__ __launch_bounds__(256) void limnet_copy_oneshot2(
    const v4f* __restrict__ um, v4f* __restrict__ out_um,
    const v4f* __restrict__ im, v4f* __restrict__ out_im) {
    int blk = blockIdx.x;
    const v4f* __restrict__ src = um;
    v4f* __restrict__ dst = out_um;
    if (blk >= NBLK_PER_MEM) {          // wave-uniform branch
        blk -= NBLK_PER_MEM;
        src = im;
        dst = out_im;
    }
    const long i = (long)blk * 256 + threadIdx.x;
    __builtin_nontemporal_store(__builtin_nontemporal_load(&src[i]), &dst[i]);
}

// K-split GRU: one block per unit; 4 waves each cover 36 of the 144 K-dims
// (9 v4f iterations), partials combined through LDS, wave 0 finishes.
__global__ __launch_bounds__(256) void limnet_gru_kernel(
    const float* __restrict__ um, const float* __restrict__ im,
    const int* __restrict__ uids, const int* __restrict__ iids,
    const float* __restrict__ ufeat, const float* __restrict__ ifeat,
    const float* __restrict__ u_w_ih, const float* __restrict__ u_b_ih,
    const float* __restrict__ u_b_hh,
    const float* __restrict__ i_w_ih, const float* __restrict__ i_b_ih,
    const float* __restrict__ i_b_hh,
    float* __restrict__ out)
{
    const int unit  = blockIdx.x;       // 0..255
    const int b     = unit >> 1;
    const int which = unit & 1;         // 0 = user GRU, 1 = item GRU
    const int t     = threadIdx.x;      // 0..255
    const int wv    = t >> 6;           // 0..3
    const int lane  = t & 63;

    __shared__ float x[INDIM];
    __shared__ float ps[4][3 * EDIM];

    const int uid = uids[b];
    const int iid = iids[b];
    const float* ue = um + ((long)b * NUSER + uid) * EDIM;
    const float* ie = im + ((long)b * NITEM + iid) * EDIM;

    // Concat layout: which==0 -> [ue, ufeat, ie, ifeat]; which==1 -> [ie, ifeat, ue, ufeat]
    const float* e1 = which ? ie : ue;
    const float* f1 = which ? (ifeat + b * FIDIM) : (ufeat + b * FUDIM);
    const float* e2 = which ? ue : ie;
    const float* f2 = which ? (ufeat + b * FUDIM) : (ifeat + b * FIDIM);

    if (t < EDIM)                     x[t] = e1[t];
    else if (t < EDIM + FUDIM)        x[t] = f1[t - EDIM];
    else if (t < 2 * EDIM + FUDIM)    x[t] = e2[t - EDIM - FUDIM];
    else if (t < INDIM)               x[t] = f2[t - 2 * EDIM - FUDIM];
    __syncthreads();

    const float* w = which ? i_w_ih : u_w_ih;
    const int k0 = wv * (INDIM / 4);    // this wave's 36-float K-chunk
    // Row bases: row*INDIM floats = row*576 B (16B aligned); +k0 floats = +144 B.
    const v4f* wr = (const v4f*)(w + (long)lane * INDIM + k0);
    const v4f* wz = (const v4f*)(w + (long)(EDIM + lane) * INDIM + k0);
    const v4f* wn = (const v4f*)(w + (long)(2 * EDIM + lane) * INDIM + k0);

    float pr = 0.f, pz = 0.f, pn = 0.f;
    #pragma unroll
    for (int k4 = 0; k4 < INDIM / 16; ++k4) {   // 9 iterations
        const v4f vr = wr[k4];
        const v4f vz = wz[k4];
        const v4f vn = wn[k4];
        const float x0 = x[k0 + 4 * k4 + 0], x1 = x[k0 + 4 * k4 + 1];
        const float x2 = x[k0 + 4 * k4 + 2], x3 = x[k0 + 4 * k4 + 3];
        pr = fmaf(vr.x, x0, pr); pr = fmaf(vr.y, x1, pr);
        pr = fmaf(vr.z, x2, pr); pr = fmaf(vr.w, x3, pr);
        pz = fmaf(vz.x, x0, pz); pz = fmaf(vz.y, x1, pz);
        pz = fmaf(vz.z, x2, pz); pz = fmaf(vz.w, x3, pz);
        pn = fmaf(vn.x, x0, pn); pn = fmaf(vn.y, x1, pn);
        pn = fmaf(vn.z, x2, pn); pn = fmaf(vn.w, x3, pn);
    }
    ps[wv][lane]            = pr;
    ps[wv][EDIM + lane]     = pz;
    ps[wv][2 * EDIM + lane] = pn;
    __syncthreads();

    if (wv == 0) {
        const float* bih = which ? i_b_ih : u_b_ih;
        const float* bhh = which ? i_b_hh : u_b_hh;
        const float gr = bih[lane] +
            ps[0][lane] + ps[1][lane] + ps[2][lane] + ps[3][lane];
        const float gz = bih[EDIM + lane] +
            ps[0][EDIM + lane] + ps[1][EDIM + lane] + ps[2][EDIM + lane] + ps[3][EDIM + lane];
        const float gn = bih[2 * EDIM + lane] +
            ps[0][2 * EDIM + lane] + ps[1][2 * EDIM + lane] + ps[2][2 * EDIM + lane] + ps[3][2 * EDIM + lane];

        // h0 == 0  =>  gh = b_hh exactly.
        const float r = 1.0f / (1.0f + expf(-(gr + bhh[lane])));
        const float z = 1.0f / (1.0f + expf(-(gz + bhh[EDIM + lane])));
        const float n = tanhf(gn + r * bhh[2 * EDIM + lane]);
        const float h = (1.0f - z) * n;     // + z*h0, h0 == 0

        // L2 normalize across the 64-lane wave.
        float s = h * h;
        #pragma unroll
        for (int off = 32; off; off >>= 1) s += __shfl_xor(s, off, 64);
        const float val = h / fmaxf(sqrtf(s), 1e-12f);

        if (which == 0) {
            out[(long)b * EDIM + lane] = val;
            out[OFF_UM + ((long)b * NUSER + uid) * EDIM + lane] = val;
        } else {
            out[OFF_NI + (long)b * EDIM + lane] = val;
            out[OFF_IM + ((long)b * NITEM + iid) * EDIM + lane] = val;
        }
    }
}

extern "C" void kernel_launch(void* const* d_in, const int* in_sizes, int n_in,
                              void* d_out, int out_size, void* d_ws, size_t ws_size,
                              hipStream_t stream) {
    const float* um    = (const float*)d_in[0];
    const float* im    = (const float*)d_in[1];
    const int*   uids  = (const int*)d_in[2];
    const int*   iids  = (const int*)d_in[3];
    const float* ufeat = (const float*)d_in[4];
    const float* ifeat = (const float*)d_in[5];
    const float* u_w_ih = (const float*)d_in[6];
    // d_in[7] = u_w_hh (unused: h0 == 0)
    const float* u_b_ih = (const float*)d_in[8];
    const float* u_b_hh = (const float*)d_in[9];
    const float* i_w_ih = (const float*)d_in[10];
    // d_in[11] = i_w_hh (unused)
    const float* i_b_ih = (const float*)d_in[12];
    const float* i_b_hh = (const float*)d_in[13];
    float* out = (float*)d_out;

    // 1) Fused one-shot copy (R7 winner): 160k blocks, 1 float4/thread, NT.
    limnet_copy_oneshot2<<<2 * NBLK_PER_MEM, 256, 0, stream>>>(
        (const v4f*)um, (v4f*)(out + OFF_UM),
        (const v4f*)im, (v4f*)(out + OFF_IM));

    // 2) K-split GRU + normalize + scatter-overwrite (4x parallel tail).
    limnet_gru_kernel<<<BATCH * 2, 256, 0, stream>>>(
        um, im, uids, iids, ufeat, ifeat,
        u_w_ih, u_b_ih, u_b_hh,
        i_w_ih, i_b_ih, i_b_hh,
        out);
}

// Round 10
// 208.503 us; speedup vs baseline: 1.2017x; 1.0215x over previous
//
#include <hip/hip_runtime.h>
#include <math.h>

#define BATCH   128
#define NUSER   10000
#define NITEM   10000
#define EDIM    64
#define FUDIM   8
#define FIDIM   8
#define INDIM   144   // 2*EDIM + FUDIM + FIDIM

typedef float v4f __attribute__((ext_vector_type(4)));

// d_out layout (floats):
// [0, 8192)                      new_user        (B x E)
// [8192, 16384)                  new_item        (B x E)
// [16384, 16384+81920000)        new_user_memory (B x NU x E)
// [16384+81920000, ...)          new_item_memory (B x NI x E)
#define OFF_NI   ((long)BATCH * EDIM)
#define OFF_UM   ((long)2 * BATCH * EDIM)
#define MEM_ELTS ((long)BATCH * NUSER * EDIM)
#define OFF_IM   (OFF_UM + MEM_ELTS)
#define NBLK_PER_MEM ((int)(MEM_ELTS / 4 / 256))   // 80,000

// Fused one-shot copy: each thread moves exactly ONE float4; first 80k
// blocks handle um, next 80k handle im. Nontemporal (streaming, no reuse).
// This structure measured 6.5+ TB/s R+W — above vendor blit (5.2) and all
// grid-stride shader variants (4.8).
__global__ __launch_bounds__(256) void limnet_copy_oneshot2(
    const v4f* __restrict__ um, v4f* __restrict__ out_um,
    const v4f* __restrict__ im, v4f* __restrict__ out_im) {
    int blk = blockIdx.x;
    const v4f* __restrict__ src = um;
    v4f* __restrict__ dst = out_um;
    if (blk >= NBLK_PER_MEM) {          // wave-uniform branch
        blk -= NBLK_PER_MEM;
        src = im;
        dst = out_im;
    }
    const long i = (long)blk * 256 + threadIdx.x;
    __builtin_nontemporal_store(__builtin_nontemporal_load(&src[i]), &dst[i]);
}

__global__ __launch_bounds__(64) void limnet_gru_kernel(
    const float* __restrict__ um, const float* __restrict__ im,
    const int* __restrict__ uids, const int* __restrict__ iids,
    const float* __restrict__ ufeat, const float* __restrict__ ifeat,
    const float* __restrict__ u_w_ih, const float* __restrict__ u_b_ih,
    const float* __restrict__ u_b_hh,
    const float* __restrict__ i_w_ih, const float* __restrict__ i_b_ih,
    const float* __restrict__ i_b_hh,
    float* __restrict__ out)
{
    const int unit  = blockIdx.x;   // 0..255
    const int b     = unit >> 1;
    const int which = unit & 1;     // 0 = user GRU, 1 = item GRU
    const int lane  = threadIdx.x;  // 0..63

    __shared__ float x[INDIM];

    const int uid = uids[b];
    const int iid = iids[b];
    const float* ue = um + ((long)b * NUSER + uid) * EDIM;
    const float* ie = im + ((long)b * NITEM + iid) * EDIM;

    // Build the 144-dim concatenated input in LDS.
    if (which == 0) {
        // [user_emb(64), user_feat(8), item_emb(64), item_feat(8)]
        x[lane] = ue[lane];
        x[EDIM + FUDIM + lane] = ie[lane];
        if (lane < FUDIM) x[EDIM + lane] = ufeat[b * FUDIM + lane];
        if (lane < FIDIM) x[EDIM + FUDIM + EDIM + lane] = ifeat[b * FIDIM + lane];
    } else {
        // [item_emb(64), item_feat(8), user_emb(64), user_feat(8)]
        x[lane] = ie[lane];
        x[EDIM + FIDIM + lane] = ue[lane];
        if (lane < FIDIM) x[EDIM + lane] = ifeat[b * FIDIM + lane];
        if (lane < FUDIM) x[EDIM + FIDIM + EDIM + lane] = ufeat[b * FUDIM + lane];
    }
    __syncthreads();

    const float* w   = which ? i_w_ih : u_w_ih;
    const float* bih = which ? i_b_ih : u_b_ih;
    const float* bhh = which ? i_b_hh : u_b_hh;

    // h0 == 0  =>  gh = b_hh exactly; GRU collapses to gates on gi only.
    float gr = bih[lane];
    float gz = bih[EDIM + lane];
    float gn = bih[2 * EDIM + lane];
    // Row base: lane*INDIM floats = lane*576 bytes -> 16B aligned, v4f ok.
    const v4f* wr = (const v4f*)(w + (long)lane * INDIM);
    const v4f* wz = (const v4f*)(w + (long)(EDIM + lane) * INDIM);
    const v4f* wn = (const v4f*)(w + (long)(2 * EDIM + lane) * INDIM);
    #pragma unroll 6
    for (int k4 = 0; k4 < INDIM / 4; ++k4) {
        const v4f vr = wr[k4];
        const v4f vz = wz[k4];
        const v4f vn = wn[k4];
        const float x0 = x[4 * k4 + 0], x1 = x[4 * k4 + 1];
        const float x2 = x[4 * k4 + 2], x3 = x[4 * k4 + 3];
        gr = fmaf(vr.x, x0, gr); gr = fmaf(vr.y, x1, gr);
        gr = fmaf(vr.z, x2, gr); gr = fmaf(vr.w, x3, gr);
        gz = fmaf(vz.x, x0, gz); gz = fmaf(vz.y, x1, gz);
        gz = fmaf(vz.z, x2, gz); gz = fmaf(vz.w, x3, gz);
        gn = fmaf(vn.x, x0, gn); gn = fmaf(vn.y, x1, gn);
        gn = fmaf(vn.z, x2, gn); gn = fmaf(vn.w, x3, gn);
    }
    const float r = 1.0f / (1.0f + expf(-(gr + bhh[lane])));
    const float z = 1.0f / (1.0f + expf(-(gz + bhh[EDIM + lane])));
    const float n = tanhf(gn + r * bhh[2 * EDIM + lane]);
    const float h = (1.0f - z) * n;     // + z*h0, h0 == 0

    // L2 normalize across the 64-lane wave.
    float s = h * h;
    #pragma unroll
    for (int off = 32; off; off >>= 1) s += __shfl_xor(s, off, 64);
    const float val = h / fmaxf(sqrtf(s), 1e-12f);

    if (which == 0) {
        out[(long)b * EDIM + lane] = val;
        out[OFF_UM + ((long)b * NUSER + uid) * EDIM + lane] = val;
    } else {
        out[OFF_NI + (long)b * EDIM + lane] = val;
        out[OFF_IM + ((long)b * NITEM + iid) * EDIM + lane] = val;
    }
}

extern "C" void kernel_launch(void* const* d_in, const int* in_sizes, int n_in,
                              void* d_out, int out_size, void* d_ws, size_t ws_size,
                              hipStream_t stream) {
    const float* um    = (const float*)d_in[0];
    const float* im    = (const float*)d_in[1];
    const int*   uids  = (const int*)d_in[2];
    const int*   iids  = (const int*)d_in[3];
    const float* ufeat = (const float*)d_in[4];
    const float* ifeat = (const float*)d_in[5];
    const float* u_w_ih = (const float*)d_in[6];
    // d_in[7] = u_w_hh (unused: h0 == 0)
    const float* u_b_ih = (const float*)d_in[8];
    const float* u_b_hh = (const float*)d_in[9];
    const float* i_w_ih = (const float*)d_in[10];
    // d_in[11] = i_w_hh (unused)
    const float* i_b_ih = (const float*)d_in[12];
    const float* i_b_hh = (const float*)d_in[13];
    float* out = (float*)d_out;

    // 1) Fused one-shot copy: 160k blocks, 1 float4/thread, NT hints.
    limnet_copy_oneshot2<<<2 * NBLK_PER_MEM, 256, 0, stream>>>(
        (const v4f*)um, (v4f*)(out + OFF_UM),
        (const v4f*)im, (v4f*)(out + OFF_IM));

    // 2) GRU + normalize + scatter-overwrite (tiny; ordered after the copy).
    limnet_gru_kernel<<<BATCH * 2, 64, 0, stream>>>(
        um, im, uids, iids, ufeat, ifeat,
        u_w_ih, u_b_ih, u_b_hh,
        i_w_ih, i_b_ih, i_b_hh,
        out);
}